// Round 18
// baseline (54.379 us; speedup 1.0000x reference)
//
#include <hip/hip_runtime.h>
#include <hip/hip_bf16.h>

typedef __attribute__((ext_vector_type(4)))  float f32x4;
typedef __attribute__((ext_vector_type(16))) float f32x16;
typedef __attribute__((ext_vector_type(8)))  short bf16x8;
typedef __attribute__((ext_vector_type(4)))  unsigned u32x4;

#define S_LEN 4096
#define HEAD_D 64
#define WIN 256
#define QBLK 128
#define KVBLK 64
#define KSTR 72
#define VSTR 72
#define QSCALE 0.18033688f   // log2(e)/8 folded into Q; no numerator shift

#define KELEM (KVBLK * KSTR)             // 4608 shorts / K buffer (9216 B)
#define VELEM (HEAD_D * VSTR)            // 4608 shorts / V buffer
#define KBYTES (KELEM * 2)
#define VOFF   (2 * KBYTES)              // V bufs after 2 K bufs
#define LPAR_OFF (VOFF + 4 * KBYTES)     // 2 K + 4 V bufs = 55296
#define SMEM_BYTES (LPAR_OFF + 2 * 4 * 32 * 4)   // 56320

static __device__ __forceinline__ unsigned cvt2(float lo, float hi) {
  unsigned r;
  asm("v_cvt_pk_bf16_f32 %0, %1, %2" : "=v"(r) : "v"(lo), "v"(hi));
  return r;
}

#define PUB_BARRIER() do {                              \
    __builtin_amdgcn_sched_barrier(0);                  \
    asm volatile("s_waitcnt lgkmcnt(0)" ::: "memory");  \
    __builtin_amdgcn_s_barrier();                       \
    __builtin_amdgcn_sched_barrier(0);                  \
  } while (0)

// Skewed pipeline: interval n = { QK(n) -> SM(n) -> pack pa(n) } || { PV(n-1) }.
// The two chains are independent -> MFMA/VALU/LDS stay fed through each other's
// latency. K 2-ring (reads of tile n end at barrier n). V 4-ring (PV(m) reads in
// interval m+1; V buf m&3 restaged at interval m+3, >=2 barriers later). pa carried
// across the barrier in 8 VGPRs.
__global__ __launch_bounds__(512, 2)
void swa_fwd(const float* __restrict__ Q, const float* __restrict__ K,
             const float* __restrict__ V, float* __restrict__ O) {
  __shared__ __attribute__((aligned(16))) char smem[SMEM_BYTES];

  const int tid  = threadIdx.x;
  const int widx = tid >> 6;
  const int lane = tid & 63;
  const int hi   = lane >> 5;
  const int c    = lane & 31;
  const int qg   = widx & 3;
  const int kh   = widx >> 2;
  const int kho  = kh * 32;

  const int pb  = blockIdx.x;
  const int bh  = (pb & 7) * 4 + ((pb >> 3) >> 5);
  const int qb  = (pb >> 3) & 31;
  const int bq0 = qb * QBLK;
  const int q0w = bq0 + qg * 32;

  const size_t base = (size_t)bh * S_LEN * HEAD_D;
  const float* Qp = Q + base;
  const float* Kp = K + base;
  const float* Vp = V + base;
  float*       Op = O + base;

  const f32x16 Z16 = {0.f,0.f,0.f,0.f,0.f,0.f,0.f,0.f,0.f,0.f,0.f,0.f,0.f,0.f,0.f,0.f};

  bf16x8 aq[4];
  {
    const float* qr = Qp + (size_t)(q0w + c) * HEAD_D + hi * 8;
    #pragma unroll
    for (int ch = 0; ch < 4; ++ch) {
      f32x4 x0 = *(const f32x4*)(qr + ch * 16);
      f32x4 x1 = *(const f32x4*)(qr + ch * 16 + 4);
      u32x4 au;
      au[0] = cvt2(x0[0] * QSCALE, x0[1] * QSCALE);
      au[1] = cvt2(x0[2] * QSCALE, x0[3] * QSCALE);
      au[2] = cvt2(x1[0] * QSCALE, x1[1] * QSCALE);
      au[3] = cvt2(x1[2] * QSCALE, x1[3] * QSCALE);
      aq[ch] = __builtin_bit_cast(bf16x8, au);
    }
  }

  f32x16 acc0 = Z16, acc1 = Z16;
  float lsA = 0.f, lsB = 0.f;

  const int lo   = max(0, bq0 - WIN);
  const int khiB = min(S_LEN, bq0 + QBLK + WIN);
  const int nt   = (khiB - lo) >> 6;   // {6,8,10}: even; main 4-unroll + optional 2-tail

  const int krow  = tid >> 3;
  const int kc8   = (tid & 7) << 3;
  const int key2  = (tid & 31) << 1;
  const int key2p = (key2 & ~12) | ((key2 & 4) << 1) | ((key2 & 8) >> 1);
  const int vd4   = (tid >> 5) << 2;

  short* const ksh = (short*)smem;
  short* const vsh = (short*)(smem + VOFF);
  const short* const krd = ksh + (kho + c) * KSTR + hi * 8;
  const short* const vrd = vsh + c * VSTR + kho + hi * 8;
  short* const kwr = ksh + krow * KSTR + kc8;
  short* const vwr = vsh + vd4 * VSTR + key2p;

  unsigned koff = (unsigned)(lo + krow) * HEAD_D + kc8;
  unsigned voff = (unsigned)(lo + key2) * HEAD_D + vd4;

  f32x4 ka0, ka1, va0, va1;
  #define LOAD_TILE() do {                          \
    ka0 = *(const f32x4*)(Kp + koff);               \
    ka1 = *(const f32x4*)(Kp + koff + 4);           \
    va0 = *(const f32x4*)(Vp + voff);               \
    va1 = *(const f32x4*)(Vp + voff + HEAD_D);      \
    koff += KVBLK * HEAD_D;                         \
    voff += KVBLK * HEAD_D;                         \
  } while (0)

  #define STAGE_TO(KB, VB) do {                                     \
    u32x4 kw;                                                       \
    kw[0] = cvt2(ka0[0], ka0[1]);                                   \
    kw[1] = cvt2(ka0[2], ka0[3]);                                   \
    kw[2] = cvt2(ka1[0], ka1[1]);                                   \
    kw[3] = cvt2(ka1[2], ka1[3]);                                   \
    *(u32x4*)&kwr[(KB) * KELEM] = kw;                               \
    _Pragma("unroll")                                               \
    for (int j = 0; j < 4; ++j)                                     \
      *(unsigned*)&vwr[(VB) * VELEM + j * VSTR] = cvt2(va0[j], va1[j]); \
  } while (0)

  // carried pipeline state
  u32x4 paAp, paBp;          // packed P of previous tile (kt=0 / kt=1)
  bool  livp = false;        // previous tile live?

  #define DO_PV(VBP) do {                                                     \
    __builtin_amdgcn_s_setprio(1);                                            \
    const bf16x8 pa0 = __builtin_bit_cast(bf16x8, paAp);                      \
    bf16x8 bv00 = *(const bf16x8*)&vrd[(VBP) * VELEM];                        \
    acc0 = __builtin_amdgcn_mfma_f32_32x32x16_bf16(pa0, bv00, acc0, 0, 0, 0); \
    bf16x8 bv01 = *(const bf16x8*)&vrd[(VBP) * VELEM + 32 * VSTR];            \
    acc1 = __builtin_amdgcn_mfma_f32_32x32x16_bf16(pa0, bv01, acc1, 0, 0, 0); \
    const bf16x8 pa1 = __builtin_bit_cast(bf16x8, paBp);                      \
    bf16x8 bv10 = *(const bf16x8*)&vrd[(VBP) * VELEM + 16];                   \
    acc0 = __builtin_amdgcn_mfma_f32_32x32x16_bf16(pa1, bv10, acc0, 0, 0, 0); \
    bf16x8 bv11 = *(const bf16x8*)&vrd[(VBP) * VELEM + 16 + 32 * VSTR];       \
    acc1 = __builtin_amdgcn_mfma_f32_32x32x16_bf16(pa1, bv11, acc1, 0, 0, 0); \
    __builtin_amdgcn_s_setprio(0);                                            \
  } while (0)

  // INTERVAL N: QK(N)+SM(N) || PV(N-1); stage N+1; load N+2; barrier.
  #define INTERVAL(N, KB, VBNXT, VBPREV) do {                                 \
    const int rel_ = lo + ((N) << 6) + kho - q0w;                             \
    const bool live_ = (rel_ >= -287) && (rel_ <= 287);                       \
    f32x16 s = Z16;                                                           \
    if (live_) {                                                              \
      __builtin_amdgcn_s_setprio(1);                                          \
      _Pragma("unroll")                                                       \
      for (int ch = 0; ch < 4; ++ch) {                                        \
        bf16x8 akf = *(const bf16x8*)&krd[(KB) * KELEM + ch * 16];            \
        s = __builtin_amdgcn_mfma_f32_32x32x16_bf16(akf, aq[ch], s, 0, 0, 0); \
      }                                                                       \
      __builtin_amdgcn_s_setprio(0);                                          \
    }                                                                         \
    if (livp) DO_PV(VBPREV);            /* independent of QK(N) chain */      \
    if ((N) + 1 < nt) {                                                       \
      STAGE_TO((KB) ^ 1, VBNXT);                                              \
      if ((N) + 2 < nt) LOAD_TILE();                                          \
    }                                                                         \
    if (live_) {                                                              \
      if (rel_ >= -224 && rel_ <= 224) {                                      \
        _Pragma("unroll")                                                     \
        for (int g = 0; g < 16; g += 2) {                                     \
          const float p0 = __builtin_amdgcn_exp2f(s[g]);                      \
          const float p1 = __builtin_amdgcn_exp2f(s[g + 1]);                  \
          s[g] = p0; s[g + 1] = p1; lsA += p0; lsB += p1;                     \
        }                                                                     \
      } else {                                                                \
        const int bm_ = rel_ + 4 * hi - c + WIN;                              \
        _Pragma("unroll")                                                     \
        for (int g = 0; g < 16; ++g) {                                        \
          const int ro_ = (g & 3) + 8 * (g >> 2);                             \
          const float p = ((unsigned)(bm_ + ro_) <= 2u * WIN)                 \
                            ? __builtin_amdgcn_exp2f(s[g]) : 0.f;             \
          s[g] = p; if (g & 1) lsB += p; else lsA += p;                       \
        }                                                                     \
      }                                                                       \
      _Pragma("unroll")                                                       \
      for (int p2 = 0; p2 < 4; ++p2) {                                        \
        paAp[p2] = cvt2(s[2 * p2], s[2 * p2 + 1]);                            \
        paBp[p2] = cvt2(s[8 + 2 * p2], s[8 + 2 * p2 + 1]);                    \
      }                                                                       \
    }                                                                         \
    livp = live_;                                                             \
    if ((N) + 1 < nt) PUB_BARRIER();                                          \
  } while (0)

  // prologue: stage tile 0 -> bufs (K0, V0); prefetch tile 1
  LOAD_TILE();
  STAGE_TO(0, 0);
  LOAD_TILE();
  PUB_BARRIER();

  int n = 0;
  for (; n + 4 <= nt; n += 4) {        // V ring phase: n&3 = 0,1,2,3
    INTERVAL(n + 0, 0, 1, 3);
    INTERVAL(n + 1, 1, 2, 0);
    INTERVAL(n + 2, 0, 3, 1);
    INTERVAL(n + 3, 1, 0, 2);
  }
  if (nt & 2) {                        // tail of 2: phases 0,1 (nt=6: n=4; nt=10: n=8)
    INTERVAL(n + 0, 0, 1, 3);
    INTERVAL(n + 1, 1, 2, 0);
  }
  // trailing PV of the last tile; its V buffer = (nt-1)&3 in {1,3}
  if (livp) {
    if (((nt - 1) & 3) == 1) DO_PV(1);
    else                     DO_PV(3);
  }

  // ---- epilogue: merge kh halves; overlay on dead K/V LDS ----
  float lsum = lsA + lsB;
  lsum += __shfl_xor(lsum, 32);
  __syncthreads();
  float* o_mrg = (float*)smem;                   // [4][32][64] = 32 KB
  float* l_par = (float*)(smem + LPAR_OFF);
  if (hi == 0) l_par[(kh * 4 + qg) * 32 + c] = lsum;
  if (kh == 0) {
    #pragma unroll
    for (int g = 0; g < 16; ++g) {
      const int qrow = (g & 3) + 8 * (g >> 2) + 4 * hi;
      o_mrg[(qg * 32 + qrow) * HEAD_D + c]      = acc0[g];
      o_mrg[(qg * 32 + qrow) * HEAD_D + 32 + c] = acc1[g];
    }
  }
  __syncthreads();
  if (kh == 1) {
    if (hi == 0) l_par[qg * 32 + c] = 1.0f / (l_par[qg * 32 + c] + l_par[(4 + qg) * 32 + c]);
    __asm__ volatile("s_waitcnt lgkmcnt(0)" ::: "memory");
    __builtin_amdgcn_sched_barrier(0);
    #pragma unroll
    for (int g = 0; g < 16; ++g) {
      const int qrow = (g & 3) + 8 * (g >> 2) + 4 * hi;
      const float iv = l_par[qg * 32 + qrow];
      float* orow = Op + (size_t)(q0w + qrow) * HEAD_D;
      orow[c]      = (o_mrg[(qg * 32 + qrow) * HEAD_D + c]      + acc0[g]) * iv;
      orow[32 + c] = (o_mrg[(qg * 32 + qrow) * HEAD_D + 32 + c] + acc1[g]) * iv;
    }
  }
}

extern "C" void kernel_launch(void* const* d_in, const int* in_sizes, int n_in,
                              void* d_out, int out_size, void* d_ws, size_t ws_size,
                              hipStream_t stream) {
  const float* q = (const float*)d_in[0];
  const float* k = (const float*)d_in[1];
  const float* v = (const float*)d_in[2];
  float* o = (float*)d_out;
  const int blocks = 2 * 16 * (S_LEN / QBLK);  // 1024
  swa_fwd<<<dim3(blocks), dim3(512), 0, stream>>>(q, k, v, o);
}

// Round 20
// 46.534 us; speedup vs baseline: 1.1686x; 1.1686x over previous
//
#include <hip/hip_runtime.h>
#include <hip/hip_bf16.h>

typedef __attribute__((ext_vector_type(4)))  float f32x4;
typedef __attribute__((ext_vector_type(16))) float f32x16;
typedef __attribute__((ext_vector_type(8)))  short bf16x8;
typedef __attribute__((ext_vector_type(4)))  unsigned u32x4;

#define S_LEN 4096
#define HEAD_D 64
#define WIN 256
#define QBLK 128
#define KVBLK 64
#define KSTR 72   // k_lds row stride (shorts)
#define VSTR 72   // vt_lds row stride (shorts), [d][key'] key' = key with bits2<->3 swapped
#define QSCALE 0.18033688f   // log2(e)/8 folded into Q; no numerator shift

#define KBYTES (KVBLK * KSTR * 2)    // 9216 B per K buffer
#define VBYTES (HEAD_D * VSTR * 2)   // 9216 B per V buffer
#define KHALF  (KBYTES / 2)          // buffer stride in shorts (4608)
#define VHALF  (VBYTES / 2)
#define LPAR_OFF (2 * KBYTES + 2 * VBYTES)          // 36864
// R19 BUG: l_inv is [2][4][32] f32 = 1024 B, was budgeted 512 -> OOB LDS write.
#define SMEM_BYTES (LPAR_OFF + 1024 + 1024)         // l_raw 1KB + l_inv 1KB = 38912

static __device__ __forceinline__ unsigned cvt2(float lo, float hi) {
  unsigned r;
  asm("v_cvt_pk_bf16_f32 %0, %1, %2" : "=v"(r) : "v"(lo), "v"(hi));
  return r;
}

// Publish barrier: drains LDS only; in-flight global prefetch loads ride across.
#define PUB_BARRIER() do {                              \
    __builtin_amdgcn_sched_barrier(0);                  \
    asm volatile("s_waitcnt lgkmcnt(0)" ::: "memory");  \
    __builtin_amdgcn_s_barrier();                       \
    __builtin_amdgcn_sched_barrier(0);                  \
  } while (0)

__global__ __launch_bounds__(512, 4)   // R11/R17-proven: VGPR 60, no spill
void swa_fwd(const float* __restrict__ Q, const float* __restrict__ K,
             const float* __restrict__ V, float* __restrict__ O) {
  __shared__ __attribute__((aligned(16))) char smem[SMEM_BYTES];

  const int tid  = threadIdx.x;
  const int widx = tid >> 6;
  const int lane = tid & 63;
  const int hi   = lane >> 5;
  const int c    = lane & 31;
  const int qg   = widx & 3;
  const int kh   = widx >> 2;
  const int kho  = kh * 32;

  // XCD swizzle: 4 contiguous bh per XCD, qb fastest.
  const int pb  = blockIdx.x;
  const int bh  = (pb & 7) * 4 + ((pb >> 3) >> 5);
  const int qb  = (pb >> 3) & 31;
  const int bq0 = qb * QBLK;
  const int q0w = bq0 + qg * 32;

  const size_t base = (size_t)bh * S_LEN * HEAD_D;
  const float* Qp = Q + base;
  const float* Kp = K + base;
  const float* Vp = V + base;
  float*       Op = O + base;

  const f32x16 Z16 = {0.f,0.f,0.f,0.f,0.f,0.f,0.f,0.f,0.f,0.f,0.f,0.f,0.f,0.f,0.f,0.f};

  // ---- Q B-fragments ----
  bf16x8 aq[4];
  {
    const float* qr = Qp + (size_t)(q0w + c) * HEAD_D + hi * 8;
    #pragma unroll
    for (int ch = 0; ch < 4; ++ch) {
      f32x4 x0 = *(const f32x4*)(qr + ch * 16);
      f32x4 x1 = *(const f32x4*)(qr + ch * 16 + 4);
      u32x4 au;
      au[0] = cvt2(x0[0] * QSCALE, x0[1] * QSCALE);
      au[1] = cvt2(x0[2] * QSCALE, x0[3] * QSCALE);
      au[2] = cvt2(x1[0] * QSCALE, x1[1] * QSCALE);
      au[3] = cvt2(x1[2] * QSCALE, x1[3] * QSCALE);
      aq[ch] = __builtin_bit_cast(bf16x8, au);
    }
  }

  f32x16 acc0 = Z16, acc1 = Z16;
  float lsA = 0.f, lsB = 0.f;

  const int lo   = max(0, bq0 - WIN);
  const int khiB = min(S_LEN, bq0 + QBLK + WIN);
  const int nt   = (khiB - lo) >> 6;   // in {6,8,10}: always even -> clean 2-unroll

  // staging lane assignment
  const int krow  = tid >> 3;
  const int kc8   = (tid & 7) << 3;
  const int key2  = (tid & 31) << 1;
  const int key2p = (key2 & ~12) | ((key2 & 4) << 1) | ((key2 & 8) >> 1);
  const int vd4   = (tid >> 5) << 2;

  // hoisted LDS bases
  short* const ksh = (short*)smem;
  short* const vsh = (short*)(smem + 2 * KBYTES);
  const short* const krd = ksh + (kho + c) * KSTR + hi * 8;     // QK reads
  const short* const vrd = vsh + c * VSTR + kho + hi * 8;       // PV reads
  short* const kwr = ksh + krow * KSTR + kc8;                   // K stage write
  short* const vwr = vsh + vd4 * VSTR + key2p;                  // V stage writes

  unsigned koff = (unsigned)(lo + krow) * HEAD_D + kc8;
  unsigned voff = (unsigned)(lo + key2) * HEAD_D + vd4;

  f32x4 ka0, ka1, va0, va1;
  #define LOAD_TILE() do {                          \
    ka0 = *(const f32x4*)(Kp + koff);               \
    ka1 = *(const f32x4*)(Kp + koff + 4);           \
    va0 = *(const f32x4*)(Vp + voff);               \
    va1 = *(const f32x4*)(Vp + voff + HEAD_D);      \
    koff += KVBLK * HEAD_D;                         \
    voff += KVBLK * HEAD_D;                         \
  } while (0)

  #define STAGE_TO(BUF) do {                                        \
    u32x4 kw;                                                       \
    kw[0] = cvt2(ka0[0], ka0[1]);                                   \
    kw[1] = cvt2(ka0[2], ka0[3]);                                   \
    kw[2] = cvt2(ka1[0], ka1[1]);                                   \
    kw[3] = cvt2(ka1[2], ka1[3]);                                   \
    *(u32x4*)&kwr[(BUF) * KHALF] = kw;                              \
    _Pragma("unroll")                                               \
    for (int j = 0; j < 4; ++j)                                     \
      *(unsigned*)&vwr[(BUF) * VHALF + j * VSTR] = cvt2(va0[j], va1[j]); \
  } while (0)

  // Tile body (R17): [QK if live] -> STAGE(t+1) -> LOAD(t+2) -> [SM -> PV if live] -> barrier
  #define TILE_BODY(T, BUF) do {                                              \
    const int rel_ = lo + ((T) << 6) + kho - q0w;                             \
    const bool live_ = (rel_ >= -287) && (rel_ <= 287);                       \
    f32x16 s = Z16;                                                           \
    if (live_) {                                                              \
      __builtin_amdgcn_s_setprio(1);                                          \
      _Pragma("unroll")                                                       \
      for (int ch = 0; ch < 4; ++ch) {                                        \
        bf16x8 akf = *(const bf16x8*)&krd[(BUF) * KHALF + ch * 16];           \
        s = __builtin_amdgcn_mfma_f32_32x32x16_bf16(akf, aq[ch], s, 0, 0, 0); \
      }                                                                       \
      __builtin_amdgcn_s_setprio(0);                                          \
    }                                                                         \
    if ((T) + 1 < nt) {                                                       \
      STAGE_TO((BUF) ^ 1);                                                    \
      if ((T) + 2 < nt) LOAD_TILE();                                          \
    }                                                                         \
    if (live_) {                                                              \
      if (rel_ >= -224 && rel_ <= 224) {                                      \
        _Pragma("unroll")                                                     \
        for (int g = 0; g < 16; g += 2) {                                     \
          const float p0 = __builtin_amdgcn_exp2f(s[g]);                      \
          const float p1 = __builtin_amdgcn_exp2f(s[g + 1]);                  \
          s[g] = p0; s[g + 1] = p1; lsA += p0; lsB += p1;                     \
        }                                                                     \
      } else {                                                                \
        const int bm_ = rel_ + 4 * hi - c + WIN;                              \
        _Pragma("unroll")                                                     \
        for (int g = 0; g < 16; ++g) {                                        \
          const int ro_ = (g & 3) + 8 * (g >> 2);                             \
          const float p = ((unsigned)(bm_ + ro_) <= 2u * WIN)                 \
                            ? __builtin_amdgcn_exp2f(s[g]) : 0.f;             \
          s[g] = p; if (g & 1) lsB += p; else lsA += p;                       \
        }                                                                     \
      }                                                                       \
      __builtin_amdgcn_s_setprio(1);                                          \
      _Pragma("unroll")                                                       \
      for (int kt = 0; kt < 2; ++kt) {                                        \
        u32x4 pau;                                                            \
        _Pragma("unroll")                                                     \
        for (int p2 = 0; p2 < 4; ++p2)                                        \
          pau[p2] = cvt2(s[kt * 8 + 2 * p2], s[kt * 8 + 2 * p2 + 1]);         \
        const bf16x8 pa = __builtin_bit_cast(bf16x8, pau);                    \
        bf16x8 bv0 = *(const bf16x8*)&vrd[(BUF) * VHALF + kt * 16];           \
        acc0 = __builtin_amdgcn_mfma_f32_32x32x16_bf16(pa, bv0, acc0, 0,0,0); \
        bf16x8 bv1 = *(const bf16x8*)&vrd[(BUF) * VHALF + kt * 16 + 32 * VSTR]; \
        acc1 = __builtin_amdgcn_mfma_f32_32x32x16_bf16(pa, bv1, acc1, 0,0,0); \
      }                                                                       \
      __builtin_amdgcn_s_setprio(0);                                          \
    }                                                                         \
    if ((T) + 1 < nt) PUB_BARRIER();                                          \
  } while (0)

  // prologue: stage tile 0 into buf 0, prefetch tile 1 (loads ride across barrier)
  LOAD_TILE();
  STAGE_TO(0);
  LOAD_TILE();
  PUB_BARRIER();

  for (int t = 0; t < nt; t += 2) {   // nt even: buffer index is compile-time
    TILE_BODY(t, 0);
    TILE_BODY(t + 1, 1);
  }

  // ---- epilogue: BALANCED d-split merge ----
  // kh0 keeps acc0 (d0-31), exports acc1; kh1 keeps acc1 (d32-63), exports acc0.
  // After one barrier each wave imports the partner's half, adds, stores its own
  // 32-column slice. Per-wave work halves vs the old kh1-does-everything merge.
  float lsum = lsA + lsB;
  lsum += __shfl_xor(lsum, 32);
  __syncthreads();                               // main-loop LDS reads done -> overlay safe
  float* mrgA  = (float*)smem;                   // [4 qg][32 q][32 d] kh0's acc1 (16 KB)
  float* mrgB  = (float*)(smem + 16384);         // [4 qg][32 q][32 d] kh1's acc0 (16 KB)
  float* l_raw = (float*)(smem + LPAR_OFF);        // [2 kh][4 qg][32] = 1 KB
  float* l_inv = (float*)(smem + LPAR_OFF + 1024); // [2 kh][4 qg][32] = 1 KB
  if (hi == 0) l_raw[(kh * 4 + qg) * 32 + c] = lsum;
  if (kh == 0) {
    #pragma unroll
    for (int g = 0; g < 16; ++g) {
      const int qrow = (g & 3) + 8 * (g >> 2) + 4 * hi;
      mrgA[(qg * 32 + qrow) * 32 + c] = acc1[g];   // lane i / i+32 same bank: 2-way = free
    }
  } else {
    #pragma unroll
    for (int g = 0; g < 16; ++g) {
      const int qrow = (g & 3) + 8 * (g >> 2) + 4 * hi;
      mrgB[(qg * 32 + qrow) * 32 + c] = acc0[g];
    }
  }
  __syncthreads();                               // publish partials + l_raw
  // per-wave-private inverse (same-wave write->read, rule #18)
  if (hi == 0) {
    const int idx = qg * 32 + c;
    l_inv[kh * 128 + idx] = 1.0f / (l_raw[idx] + l_raw[128 + idx]);
  }
  __asm__ volatile("s_waitcnt lgkmcnt(0)" ::: "memory");
  __builtin_amdgcn_sched_barrier(0);
  if (kh == 0) {
    #pragma unroll
    for (int g = 0; g < 16; ++g) {
      const int qrow = (g & 3) + 8 * (g >> 2) + 4 * hi;
      const float iv = l_inv[qg * 32 + qrow];      // lane-uniform -> LDS broadcast
      Op[(size_t)(q0w + qrow) * HEAD_D + c] =
          (acc0[g] + mrgB[(qg * 32 + qrow) * 32 + c]) * iv;
    }
  } else {
    #pragma unroll
    for (int g = 0; g < 16; ++g) {
      const int qrow = (g & 3) + 8 * (g >> 2) + 4 * hi;
      const float iv = l_inv[128 + qg * 32 + qrow];
      Op[(size_t)(q0w + qrow) * HEAD_D + 32 + c] =
          (acc1[g] + mrgA[(qg * 32 + qrow) * 32 + c]) * iv;
    }
  }
}

extern "C" void kernel_launch(void* const* d_in, const int* in_sizes, int n_in,
                              void* d_out, int out_size, void* d_ws, size_t ws_size,
                              hipStream_t stream) {
  const float* q = (const float*)d_in[0];
  const float* k = (const float*)d_in[1];
  const float* v = (const float*)d_in[2];
  float* o = (float*)d_out;
  const int blocks = 2 * 16 * (S_LEN / QBLK);  // 1024
  swa_fwd<<<dim3(blocks), dim3(512), 0, stream>>>(q, k, v, o);
}